// Round 1
// baseline (103.455 us; speedup 1.0000x reference)
//
#include <hip/hip_runtime.h>
#include <hip/hip_bf16.h>

typedef short short8 __attribute__((ext_vector_type(8)));
typedef float f32x4 __attribute__((ext_vector_type(4)));

__device__ __forceinline__ unsigned short f2bf(float f) {
    union { float f; unsigned int i; } v; v.f = f;
    unsigned int i = v.i;
    unsigned int r = (i + 0x7fffu + ((i >> 16) & 1u)) >> 16;   // RNE
    return (unsigned short)r;
}

// packed f32->bf16 (RNE), lo -> bits[15:0], hi -> bits[31:16]
__device__ __forceinline__ unsigned int cvtpk_bf16(float lo, float hi) {
    unsigned int r;
    asm("v_cvt_pk_bf16_f32 %0, %1, %2" : "=v"(r) : "v"(lo), "v"(hi));
    return r;
}

// sum over the 16 lanes sharing lane&3 (reduce bits 2..5 of the lane id)
__device__ __forceinline__ float xred16(float v) {
    v += __shfl_xor(v, 4);
    v += __shfl_xor(v, 8);
    v += __shfl_xor(v, 16);
    v += __shfl_xor(v, 32);
    return v;
}

// One block per node (b,n). 256 threads. N=256, B=2 fixed by problem shape.
__global__ __launch_bounds__(256, 2)
void tpconv_kernel(const float* __restrict__ node_attr,   // [B,256,64]
                   const float* __restrict__ edge_attr,   // [B,256,256,32]
                   const float* __restrict__ edge_sh,     // [B,256,256,4]
                   const float* __restrict__ mask,        // [B,256]
                   const float* __restrict__ wlis,        // [16,16]
                   const float* __restrict__ wliv,        // [16,16]
                   const float* __restrict__ fc_w1,       // [32,32]
                   const float* __restrict__ fc_b1,       // [32]
                   const float* __restrict__ fc_w2,       // [32,1024]
                   const float* __restrict__ fc_b2,       // [1024]
                   const float* __restrict__ wlos,        // [16,16]
                   const float* __restrict__ wlov,        // [16,16]
                   float* __restrict__ out)               // [B,256,64]
{
    const int node = blockIdx.x;      // b*256 + n
    const int b = node >> 8;
    const int n = node & 255;
    const int t = threadIdx.x;

    __shared__ __align__(16) unsigned short s_w1t[32 * 32];   // fc_w1 transposed [f][k] (bf16)
    __shared__ __align__(16) float s_wc[4 * 256];             // per-edge weights (sh_s, sh_v xyz)*mask
    __shared__ float s_b1[32];
    __shared__ float s_wmask[4];
    __shared__ __align__(16) float s_wp[512];                 // per-wave moment partials [w][c][f]
    __shared__ float s_wp0[16];                               // per-wave bias-moment partials [w][c]
    __shared__ __align__(16) float s_momT[128];               // moments transposed [f][c]
    __shared__ float s_mom0[4];
    __shared__ float s_scale;
    __shared__ float s_sin[16];                               // s_in
    __shared__ float s_vin[48];                               // v_in[o][x] at o*3+x
    __shared__ float s_preA[16], s_preB[16];                  // pre partials (ss | vv)
    __shared__ float s_prevA[48], s_prevB[48];                // prev partials (sv | vs)

    // ---------------- Phase 0: small staging only ----------------
    {
        float mk = mask[(b << 8) + t];
        float ms = mk;
        ms += __shfl_xor(ms, 1);  ms += __shfl_xor(ms, 2);  ms += __shfl_xor(ms, 4);
        ms += __shfl_xor(ms, 8);  ms += __shfl_xor(ms, 16); ms += __shfl_xor(ms, 32);
        if ((t & 63) == 0) s_wmask[t >> 6] = ms;
        float excl = (t == n) ? 0.0f : mk;   // mask out self-edge
        const float4 sh4 = *(const float4*)(edge_sh + ((size_t)node * 256 + t) * 4);
        s_wc[0 * 256 + t] = excl * sh4.x;
        s_wc[1 * 256 + t] = excl * sh4.y;
        s_wc[2 * 256 + t] = excl * sh4.z;
        s_wc[3 * 256 + t] = excl * sh4.w;
    }
    {
        #pragma unroll
        for (int jj = 0; jj < 4; ++jj) {
            int e = t * 4 + jj;
            int f = e >> 5, k = e & 31;
            s_w1t[e] = f2bf(fc_w1[k * 32 + f]);   // s_w1t[f*32+k] = W1[k][f]
        }
        if (t < 32) s_b1[t] = fc_b1[t];
    }
    // input linears: spread across wave1 (vin) and wave2 (sin)
    if (t >= 128 && t < 144) {
        int o = t - 128;
        const float* na = node_attr + (size_t)node * 64;
        float a = 0.f;
        #pragma unroll
        for (int i = 0; i < 16; ++i) a += na[i] * wlis[i * 16 + o];
        s_sin[o] = a * 0.25f;    // / sqrt(16)
    } else if (t >= 80 && t < 128) {
        int idx = t - 80;
        int o = idx / 3, x = idx - o * 3;
        const float* na = node_attr + (size_t)node * 64;
        float a = 0.f;
        #pragma unroll
        for (int i = 0; i < 16; ++i) a += na[16 + i * 3 + x] * wliv[i * 16 + o];
        s_vin[idx] = a * 0.25f;
    }
    __syncthreads();

    // ------- Phase 1: h = relu(ea@W1 + b1) via MFMA (A direct from global), fold moments -------
    {
        const int wv = t >> 6;          // wave 0..3
        const int ln = t & 63;
        const int q  = ln >> 4;         // quad
        const int fc = ln & 15;
        // B-fragments: lane holds B[k][n]=W1[k][f] for f=fc(+16), k=q*8+j  -> W1T rows
        short8 bf0 = *(const short8*)&s_w1t[fc * 32 + q * 8];
        short8 bf1 = *(const short8*)&s_w1t[(16 + fc) * 32 + q * 8];
        float b1a = s_b1[fc], b1b = s_b1[16 + fc];
        // A-fragment source: lane (q,fc) needs row T*16+fc, k = q*8..q*8+7 (32 B)
        const float* ea = edge_attr + (size_t)node * 8192 + fc * 32 + q * 8;
        float pmc[4][2] = {{0,0},{0,0},{0,0},{0,0}};
        float pm0[4] = {0,0,0,0};
        #pragma unroll
        for (int tt = 0; tt < 4; ++tt) {
            const int T = wv * 4 + tt;          // edge tile (16 edges)
            const float4 a0 = *(const float4*)(ea + (size_t)T * 512);
            const float4 a1 = *(const float4*)(ea + (size_t)T * 512 + 4);
            union { unsigned int u[4]; short8 s; } cv;
            cv.u[0] = cvtpk_bf16(a0.x, a0.y);
            cv.u[1] = cvtpk_bf16(a0.z, a0.w);
            cv.u[2] = cvtpk_bf16(a1.x, a1.y);
            cv.u[3] = cvtpk_bf16(a1.z, a1.w);
            f32x4 z = {0.f, 0.f, 0.f, 0.f};
            f32x4 acc0 = __builtin_amdgcn_mfma_f32_16x16x32_bf16(cv.s, bf0, z, 0, 0, 0);
            f32x4 acc1 = __builtin_amdgcn_mfma_f32_16x16x32_bf16(cv.s, bf1, z, 0, 0, 0);
            // C layout: lane(q,fc) reg r -> h[edge=T*16+q*4+r][f=fc(+16)]
            f32x4 w0 = *(const f32x4*)&s_wc[0 * 256 + T * 16 + q * 4];
            f32x4 w1 = *(const f32x4*)&s_wc[1 * 256 + T * 16 + q * 4];
            f32x4 w2 = *(const f32x4*)&s_wc[2 * 256 + T * 16 + q * 4];
            f32x4 w3 = *(const f32x4*)&s_wc[3 * 256 + T * 16 + q * 4];
            #pragma unroll
            for (int r = 0; r < 4; ++r) {
                float h0 = acc0[r] + b1a; h0 = h0 > 0.f ? h0 : 0.f;
                float h1 = acc1[r] + b1b; h1 = h1 > 0.f ? h1 : 0.f;
                float wr0 = w0[r], wr1 = w1[r], wr2 = w2[r], wr3 = w3[r];
                pmc[0][0] += h0 * wr0; pmc[0][1] += h1 * wr0;
                pmc[1][0] += h0 * wr1; pmc[1][1] += h1 * wr1;
                pmc[2][0] += h0 * wr2; pmc[2][1] += h1 * wr2;
                pmc[3][0] += h0 * wr3; pmc[3][1] += h1 * wr3;
                pm0[0] += wr0; pm0[1] += wr1; pm0[2] += wr2; pm0[3] += wr3;
            }
        }
        // reduce across quads (lanes differing in bits 4,5 share f)
        #pragma unroll
        for (int c = 0; c < 4; ++c) {
            #pragma unroll
            for (int ft = 0; ft < 2; ++ft) {
                float v = pmc[c][ft];
                v += __shfl_xor(v, 16);
                v += __shfl_xor(v, 32);
                if (q == 0) s_wp[(wv * 4 + c) * 32 + ft * 16 + fc] = v;
            }
            float v0 = pm0[c];
            v0 += __shfl_xor(v0, 16);
            v0 += __shfl_xor(v0, 32);
            if (ln == 0) s_wp0[wv * 4 + c] = v0;
        }
    }
    __syncthreads();

    // ---------------- Phase 2: combine wave partials (transposed moments) ----------------
    if (t < 128) {
        int c = t >> 5, f = t & 31;
        s_momT[f * 4 + c] = s_wp[(0 + c) * 32 + f] + s_wp[(4 + c) * 32 + f]
                          + s_wp[(8 + c) * 32 + f] + s_wp[(12 + c) * 32 + f];
    } else if (t == 128) {
        #pragma unroll
        for (int c = 0; c < 4; ++c)
            s_mom0[c] = s_wp0[c] + s_wp0[4 + c] + s_wp0[8 + c] + s_wp0[12 + c];
    } else if (t == 129) {
        float ds = s_wmask[0] + s_wmask[1] + s_wmask[2] + s_wmask[3] - 1.0f;
        s_scale = 0.17677669529663687f / ds;   // inv_fan / dsum
    }
    __syncthreads();

    // ------- Phase 3+4a fused: one wave per W2 block; contract with sin/vin in-register -------
    // wave g=0: ss (c=0, x sin -> preA)       g=1: vv (c=1..3 folded with vin -> preB)
    // wave g=2: sv (c=1..3, x sin -> prevA)   g=3: vs (c=0, x vin -> prevB)
    {
        const int g   = t >> 6;
        const int j   = t & 63;
        const int i16 = j >> 2;                 // eff row i (cols j*4.. are i16*16 + o)
        const float* w2g = fc_w2 + g * 256 + j * 4;
        const f32x4 b2v = *(const f32x4*)(fc_b2 + g * 256 + j * 4);
        const float si = s_sin[i16];
        const float vx = s_vin[i16 * 3 + 0], vy = s_vin[i16 * 3 + 1], vz = s_vin[i16 * 3 + 2];

        if (g == 0) {
            const float m0 = s_mom0[0];
            f32x4 acc; acc[0] = m0 * b2v[0]; acc[1] = m0 * b2v[1]; acc[2] = m0 * b2v[2]; acc[3] = m0 * b2v[3];
            #pragma unroll
            for (int f = 0; f < 32; ++f) {
                f32x4 wv4 = *(const f32x4*)(w2g + f * 1024);
                float mv = s_momT[f * 4 + 0];
                acc[0] += mv * wv4[0]; acc[1] += mv * wv4[1]; acc[2] += mv * wv4[2]; acc[3] += mv * wv4[3];
            }
            float p0 = xred16(si * acc[0]), p1 = xred16(si * acc[1]);
            float p2 = xred16(si * acc[2]), p3 = xred16(si * acc[3]);
            if (j < 4) { s_preA[j * 4 + 0] = p0; s_preA[j * 4 + 1] = p1;
                         s_preA[j * 4 + 2] = p2; s_preA[j * 4 + 3] = p3; }
        } else if (g == 1) {
            const float cm0 = vx * s_mom0[1] + vy * s_mom0[2] + vz * s_mom0[3];
            f32x4 acc; acc[0] = cm0 * b2v[0]; acc[1] = cm0 * b2v[1]; acc[2] = cm0 * b2v[2]; acc[3] = cm0 * b2v[3];
            #pragma unroll
            for (int f = 0; f < 32; ++f) {
                f32x4 wv4 = *(const f32x4*)(w2g + f * 1024);
                f32x4 mv4 = *(const f32x4*)&s_momT[f * 4];
                float cmf = vx * mv4[1] + vy * mv4[2] + vz * mv4[3];
                acc[0] += cmf * wv4[0]; acc[1] += cmf * wv4[1]; acc[2] += cmf * wv4[2]; acc[3] += cmf * wv4[3];
            }
            float p0 = xred16(acc[0]), p1 = xred16(acc[1]);
            float p2 = xred16(acc[2]), p3 = xred16(acc[3]);
            if (j < 4) { s_preB[j * 4 + 0] = p0; s_preB[j * 4 + 1] = p1;
                         s_preB[j * 4 + 2] = p2; s_preB[j * 4 + 3] = p3; }
        } else if (g == 2) {
            float ax[3][4];
            #pragma unroll
            for (int x = 0; x < 3; ++x) {
                float m0x = s_mom0[1 + x];
                #pragma unroll
                for (int k = 0; k < 4; ++k) ax[x][k] = m0x * b2v[k];
            }
            #pragma unroll
            for (int f = 0; f < 32; ++f) {
                f32x4 wv4 = *(const f32x4*)(w2g + f * 1024);
                f32x4 mv4 = *(const f32x4*)&s_momT[f * 4];
                #pragma unroll
                for (int k = 0; k < 4; ++k) {
                    ax[0][k] += mv4[1] * wv4[k];
                    ax[1][k] += mv4[2] * wv4[k];
                    ax[2][k] += mv4[3] * wv4[k];
                }
            }
            #pragma unroll
            for (int x = 0; x < 3; ++x)
                #pragma unroll
                for (int k = 0; k < 4; ++k) {
                    float p = xred16(si * ax[x][k]);
                    if (j < 4) s_prevA[(j * 4 + k) * 3 + x] = p;
                }
        } else {   // g == 3 : vs
            const float m0 = s_mom0[0];
            f32x4 acc; acc[0] = m0 * b2v[0]; acc[1] = m0 * b2v[1]; acc[2] = m0 * b2v[2]; acc[3] = m0 * b2v[3];
            #pragma unroll
            for (int f = 0; f < 32; ++f) {
                f32x4 wv4 = *(const f32x4*)(w2g + f * 1024);
                float mv = s_momT[f * 4 + 0];
                acc[0] += mv * wv4[0]; acc[1] += mv * wv4[1]; acc[2] += mv * wv4[2]; acc[3] += mv * wv4[3];
            }
            float vcomp[3] = {vx, vy, vz};
            #pragma unroll
            for (int x = 0; x < 3; ++x)
                #pragma unroll
                for (int k = 0; k < 4; ++k) {
                    float p = xred16(vcomp[x] * acc[k]);
                    if (j < 4) s_prevB[(j * 4 + k) * 3 + x] = p;
                }
        }
    }
    __syncthreads();

    // ---------------- Phase 4b: output linear + residual ----------------
    if (t < 16) {
        const float sc = s_scale * 0.25f;
        float a = 0.f;
        #pragma unroll
        for (int ii = 0; ii < 16; ++ii) {
            float pre = s_preA[ii] + s_preB[ii] * 0.5773502691896258f;   // + vv/sqrt(3)
            a += pre * wlos[ii * 16 + t];
        }
        const float* na = node_attr + (size_t)node * 64;
        out[(size_t)node * 64 + t] = a * sc + na[t];
    } else if (t < 64) {
        int idx = t - 16;
        int o = idx / 3, x = idx - o * 3;
        const float sc = s_scale * 0.25f;
        float a = 0.f;
        #pragma unroll
        for (int ii = 0; ii < 16; ++ii)
            a += (s_prevA[ii * 3 + x] + s_prevB[ii * 3 + x]) * wlov[ii * 16 + o];
        const float* na = node_attr + (size_t)node * 64;
        out[(size_t)node * 64 + 16 + idx] = a * sc + na[16 + idx];
    }
}

extern "C" void kernel_launch(void* const* d_in, const int* in_sizes, int n_in,
                              void* d_out, int out_size, void* d_ws, size_t ws_size,
                              hipStream_t stream) {
    (void)n_in; (void)d_ws; (void)ws_size; (void)out_size;
    const float* node_attr = (const float*)d_in[0];
    const float* edge_attr = (const float*)d_in[1];
    const float* edge_sh   = (const float*)d_in[2];
    const float* maskp     = (const float*)d_in[3];
    const float* wlis      = (const float*)d_in[4];
    const float* wliv      = (const float*)d_in[5];
    const float* fc_w1     = (const float*)d_in[6];
    const float* fc_b1     = (const float*)d_in[7];
    const float* fc_w2     = (const float*)d_in[8];
    const float* fc_b2     = (const float*)d_in[9];
    const float* wlos      = (const float*)d_in[10];
    const float* wlov      = (const float*)d_in[11];
    float* outp = (float*)d_out;

    int nodes = in_sizes[0] / 64;   // B*N = 512
    tpconv_kernel<<<dim3(nodes), dim3(256), 0, stream>>>(
        node_attr, edge_attr, edge_sh, maskp, wlis, wliv,
        fc_w1, fc_b1, fc_w2, fc_b2, wlos, wlov, outp);
}